// Round 19
// baseline (151.610 us; speedup 1.0000x reference)
//
#include <hip/hip_runtime.h>

// DCNv4 3D — round 19: round-18 base with EXACTLY ONE change: proj GEMM
// ct-range split across grid.y=2 (cts 0-15 / 16-30). Grid 1024->2048 blocks
// -> 6 resident blocks/CU (was 4, all barrier-locked) so iteration stalls
// overlap across independent blocks. A-fragments loaded twice (+17MB, ~3µs).

typedef _Float16 f16;
typedef _Float16 f16x8 __attribute__((ext_vector_type(8)));
typedef _Float16 f16x4 __attribute__((ext_vector_type(4)));
typedef _Float16 f16x2 __attribute__((ext_vector_type(2)));
typedef float    f32x4 __attribute__((ext_vector_type(4)));

#define NB 2
#define DIM 32
#define CC 128
#define GG 8
#define CG 16
#define KPTS 27
#define LL (DIM*DIM*DIM)  // 32768
#define MM (NB*LL)        // 65536
#define OMD 864
#define PXW (CC + OMD)    // 992

// halo geometry (uint4 units): v = lz*192 + ly*24 + lx ; chd plane 1536
#define SZV 192
#define SYV 24
#define PLANE 1536

// B-panel LDS row stride (f16)
#define BST 152

__device__ __forceinline__ f16x2 pkrtz(float a, float b) {
  return __builtin_bit_cast(f16x2, __builtin_amdgcn_cvt_pkrtz(a, b));
}

// ---- merged prologue (round-17 verbatim) ----
#define T_WCAT (PXW * 32)
#define T_WOUT (CC * CC / 4)
#define T_ALL  (T_WCAT + T_WOUT + PXW)
__global__ __launch_bounds__(256) void build_pre(
    const float* __restrict__ vw, const float* __restrict__ ow,
    const float* __restrict__ vb, const float* __restrict__ ob,
    const float* __restrict__ outw, f16* __restrict__ wcat,
    float* __restrict__ pbias, f16* __restrict__ wout) {
  int t = blockIdx.x * 256 + threadIdx.x;
  if (t < T_WCAT) {
    int p = t >> 5, c4 = (t & 31) * 4;
    const float* src;
    if (p < CC) {
      src = vw + (size_t)p * CC;
    } else {
      int q = p - CC, g = q / 108, r = q % 108, k = r >> 2, j = r & 3;
      src = ow + (size_t)(g * 108 + (j < 3 ? k * 3 + j : 81 + k)) * CC;
    }
    float4 v = *(const float4*)(src + c4);
    f16x4 o = {(f16)v.x, (f16)v.y, (f16)v.z, (f16)v.w};
    *(f16x4*)(wcat + (size_t)p * CC + c4) = o;
    return;
  }
  int u = t - T_WCAT;
  if (u < T_WOUT) {
    float4 v = ((const float4*)outw)[u];
    f16x4 o = {(f16)v.x, (f16)v.y, (f16)v.z, (f16)v.w};
    ((f16x4*)wout)[u] = o;
    return;
  }
  int p = u - T_WOUT;
  if (p < PXW) {
    float v;
    if (p < CC) v = vb[p];
    else {
      int q = p - CC, g = q / 108, r = q % 108, k = r >> 2, j = r & 3;
      v = ob[g * 108 + (j < 3 ? k * 3 + j : 81 + k)];
    }
    pbias[p] = v;
  }
}

// ---------------- proj GEMM: ct-split across grid.y ----------------------
// Block = 4 waves x 64 rows, A reg-cached; B-panel (8KB) staged in LDS per
// ct, double-buffered, one __syncthreads per iteration.
__global__ __launch_bounds__(256) void gemm_proj(
    const float* __restrict__ A, const f16* __restrict__ B,
    const float* __restrict__ bias, f16* __restrict__ xg,
    f16* __restrict__ om) {
  __shared__ f16 bs[2][32 * BST];      // 19456 B
  __shared__ f16 tr[4][16 * 40];       // 5120 B
  const int tid  = threadIdx.x;
  const int w    = tid >> 6;
  const int lane = tid & 63;
  const int rowBase = blockIdx.x * 64 + w * 16;
  const int r  = lane & 15;
  const int kg = lane >> 4;
  const int ctBegin = blockIdx.y * 16;
  const int ctEnd   = min(31, ctBegin + 16);

  f16x8 a[4];
  {
    const float* Ap = A + (size_t)(rowBase + r) * CC + kg * 8;
#pragma unroll
    for (int kk = 0; kk < 4; ++kk) {
      float4 lo = *(const float4*)(Ap + kk * 32);
      float4 hi = *(const float4*)(Ap + kk * 32 + 4);
      f16x8 t;
      t[0] = (f16)lo.x; t[1] = (f16)lo.y; t[2] = (f16)lo.z; t[3] = (f16)lo.w;
      t[4] = (f16)hi.x; t[5] = (f16)hi.y; t[6] = (f16)hi.z; t[7] = (f16)hi.w;
      a[kk] = t;
    }
  }

  uint4 stg0, stg1;
  const int i0 = tid, i1 = tid + 256;
  const int d0 = (i0 >> 4) * BST + (i0 & 15) * 8;
  const int d1 = (i1 >> 4) * BST + (i1 & 15) * 8;

  {
    const f16* src = B + ctBegin * 4096;
    stg0 = *(const uint4*)(src + i0 * 8);
    stg1 = *(const uint4*)(src + i1 * 8);
    *(uint4*)(bs[0] + d0) = stg0;
    *(uint4*)(bs[0] + d1) = stg1;
  }
  __syncthreads();

  f16* tw = tr[w];
  for (int ct = ctBegin; ct < ctEnd; ++ct) {
    const int buf = (ct - ctBegin) & 1;
    if (ct + 1 < ctEnd) {
      const f16* src = B + (ct + 1) * 4096;
      stg0 = *(const uint4*)(src + i0 * 8);
      stg1 = *(const uint4*)(src + i1 * 8);
    }
    const f16* bp = bs[buf];
    f32x4 acc0 = {0.f, 0.f, 0.f, 0.f};
    f32x4 acc1 = {0.f, 0.f, 0.f, 0.f};
#pragma unroll
    for (int kk = 0; kk < 4; ++kk) {
      f16x8 b0 = *(const f16x8*)(bp + r * BST + kg * 8 + kk * 32);
      f16x8 b1 = *(const f16x8*)(bp + (r + 16) * BST + kg * 8 + kk * 32);
      acc0 = __builtin_amdgcn_mfma_f32_16x16x32_f16(a[kk], b0, acc0, 0, 0, 0);
      acc1 = __builtin_amdgcn_mfma_f32_16x16x32_f16(a[kk], b1, acc1, 0, 0, 0);
    }
    const int colBase = ct * 32;
    const float bv0 = bias[colBase + r];
    const float bv1 = bias[colBase + 16 + r];
#pragma unroll
    for (int i = 0; i < 4; ++i) {
      const int trow = kg * 4 + i;
      tw[trow * 40 + r]      = (f16)(acc0[i] + bv0);
      tw[trow * 40 + 16 + r] = (f16)(acc1[i] + bv1);
    }
    asm volatile("s_waitcnt lgkmcnt(0)" ::: "memory");
    const int lrow = lane >> 2;
    const int c8   = (lane & 3) * 8;
    uint4 val = *(const uint4*)(tw + lrow * 40 + c8);
    const int row  = rowBase + lrow;
    if (ct < 4) {
      const int nn = row >> 15, flat = row & (LL - 1);
      const int g  = ct * 2 + ((lane >> 1) & 1);
      unsigned e = ((unsigned)((g * 2 + nn) << 15) + flat) * 16 + (lane & 1) * 8;
      *(uint4*)(xg + e) = val;
    } else {
      const int q0 = ct * 8 - 32 + (lane & 3) * 2;
      uint2 s0, s1;
      s0.x = val.x; s0.y = val.y;
      s1.x = val.z; s1.y = val.w;
      *(uint2*)(om + ((size_t)q0 * MM + row) * 4)       = s0;
      *(uint2*)(om + ((size_t)(q0 + 1) * MM + row) * 4) = s1;
    }
    asm volatile("s_waitcnt lgkmcnt(0)" ::: "memory");
    if (ct + 1 < ctEnd) {
      *(uint4*)(bs[buf ^ 1] + d0) = stg0;
      *(uint4*)(bs[buf ^ 1] + d1) = stg1;
    }
    __syncthreads();
  }
}

// ---------------- out GEMM (round-17 verbatim) ---------------------------
__global__ __launch_bounds__(256) void gemm_out(
    const f16* __restrict__ Ain, const f16* __restrict__ B,
    const float* __restrict__ bias, float* __restrict__ fout) {
  const int w    = threadIdx.x >> 6;
  const int lane = threadIdx.x & 63;
  const int rowBase = blockIdx.x * 64 + w * 16;
  const int r  = lane & 15;
  const int kg = lane >> 4;
  const int ctBegin = blockIdx.y * 2;

  f16x8 a[4];
  const f16* A = Ain + (size_t)(rowBase + r) * CC + kg * 8;
#pragma unroll
  for (int kk = 0; kk < 4; ++kk) a[kk] = *(const f16x8*)(A + kk * 32);

  f16x8 bb[2][8];
#pragma unroll
  for (int s = 0; s < 2; ++s) {
    const f16* Bp = B + (unsigned)((ctBegin + s) * 32 + r) * CC + kg * 8;
#pragma unroll
    for (int kk = 0; kk < 4; ++kk) {
      bb[s][kk]     = *(const f16x8*)(Bp + kk * 32);
      bb[s][4 + kk] = *(const f16x8*)(Bp + 16 * CC + kk * 32);
    }
  }

#pragma unroll
  for (int t = 0; t < 2; ++t) {
    const int colBase = (ctBegin + t) * 32;
    f32x4 acc0 = {0.f, 0.f, 0.f, 0.f};
    f32x4 acc1 = {0.f, 0.f, 0.f, 0.f};
#pragma unroll
    for (int kk = 0; kk < 4; ++kk) {
      acc0 = __builtin_amdgcn_mfma_f32_16x16x32_f16(a[kk], bb[t][kk], acc0, 0, 0, 0);
      acc1 = __builtin_amdgcn_mfma_f32_16x16x32_f16(a[kk], bb[t][4 + kk], acc1, 0, 0, 0);
    }
    const float bv0 = bias[colBase + r];
    const float bv1 = bias[colBase + 16 + r];
    const int drow = rowBase + kg * 4;
    const int c0 = colBase + r, c1 = c0 + 16;
#pragma unroll
    for (int i = 0; i < 4; ++i) {
      unsigned ro = (unsigned)(drow + i) * CC;
      fout[ro + c0] = acc0[i] + bv0;
      fout[ro + c1] = acc1[i] + bv1;
    }
  }
}

// ---------------- DCNv4 sampling core v11 (round-18 verbatim) ------------
__global__ __launch_bounds__(256) void dcn_core(const f16* __restrict__ xg,
                                                const f16* __restrict__ om,
                                                f16* __restrict__ y) {
  __shared__ uint4 ldsx[2 * PLANE];   // 49152 B

  const int tid = threadIdx.x;
  int bid = blockIdx.x;
  const int g   = bid & 7;        bid >>= 3;
  const int n   = bid & 1;        bid >>= 1;
  const int tx0 = (bid & 1) * 16; bid >>= 1;
  const int ty0 = (bid & 7) * 4;  bid >>= 3;
  const int tz0 = bid * 4;

  // ---- stage halo 8z x 8y x 20x, zero-padded ----
  const f16* xgb = xg + (((size_t)(g * 2 + n)) << 15) * 16;
#pragma unroll
  for (int it = 0; it < 5; ++it) {
    int v = tid + it * 256;            // 0..1279
    int lz = v / 160, r160 = v - lz * 160;
    int ly = r160 / 20, lx = r160 - ly * 20;
    int gz = tz0 - 2 + lz, gy = ty0 - 2 + ly, gx = tx0 - 2 + lx;
    uint4 d0 = {0u, 0u, 0u, 0u}, d1 = {0u, 0u, 0u, 0u};
    if (((unsigned)gz < DIM) & ((unsigned)gy < DIM) & ((unsigned)gx < DIM)) {
      const uint4* src = (const uint4*)(xgb + (size_t)(((gz << 5) + gy) * 32 + gx) * 16);
      d0 = src[0];
      d1 = src[1];
    }
    int vv = lz * SZV + ly * SYV + lx;
    ldsx[vv]         = d0;
    ldsx[PLANE + vv] = d1;
  }
  __syncthreads();

  // ---- sampling: lane = position ----
  const int px = tid & 15, py = (tid >> 4) & 3, pz = tid >> 6;
  const int dz = tz0 + pz, dy = ty0 + py, dx = tx0 + px;
  const unsigned row = (unsigned)(n << 15) + ((dz << 10) + (dy << 5) + dx);

  const int zoff = tz0 - 2, yoff = ty0 - 2, xoff = tx0 - 2;
  const int pb = g * 27;                    // om plane base

  float dyf[3], dxf[3];
#pragma unroll
  for (int t = 0; t < 3; ++t) { dyf[t] = (float)(dy + t - 1); dxf[t] = (float)(dx + t - 1); }

  f16x2 a0 = {(f16)0, (f16)0}, a1 = a0, a2 = a0, a3 = a0;
  f16x2 a4 = a0, a5 = a0, a6 = a0, a7 = a0;
  const float CL = 0.99902344f;

  for (int kz = 0; kz < 3; ++kz) {
    const float bzf = (float)(dz + kz - 1);
    uint2 o[9];
#pragma unroll
    for (int j = 0; j < 9; ++j)
      o[j] = *(const uint2*)(om + ((size_t)(pb + kz * 9 + j) * MM + row) * 4);
#pragma unroll
    for (int j = 0; j < 9; ++j) {
      const int kh = j / 3, kw = j % 3;
      f16x2 o01 = __builtin_bit_cast(f16x2, o[j].x);
      f16x2 o23 = __builtin_bit_cast(f16x2, o[j].y);
      float od = fminf(fmaxf((float)o01[0], -CL), CL);
      float oh = fminf(fmaxf((float)o01[1], -CL), CL);
      float ow = fminf(fmaxf((float)o23[0], -CL), CL);
      float m  = (float)o23[1];
      float pd = bzf + od;
      float ph = dyf[kh] + oh;
      float pw = dxf[kw] + ow;
      float fd = floorf(pd), fh = floorf(ph), fw = floorf(pw);
      float td = pd - fd, th = ph - fh, tw = pw - fw;
      int id = (int)fd, ih = (int)fh, iw = (int)fw;
      float wz0 = (1.f - td) * m, wz1 = td * m;
      float wy0 = 1.f - th,        wy1 = th;
      float wx0 = 1.f - tw,        wx1 = tw;
      int az0 = (id - zoff) * SZV, az1 = az0 + SZV;
      int ay0 = (ih - yoff) * SYV, ay1 = ay0 + SYV;
      int ax0 = (iw - xoff), ax1 = ax0 + 1;
      float wzy00 = wz0 * wy0, wzy01 = wz0 * wy1;
      float wzy10 = wz1 * wy0, wzy11 = wz1 * wy1;
#pragma unroll
      for (int c = 0; c < 8; ++c) {
        int idx = ((c & 4) ? az1 : az0) + ((c & 2) ? ay1 : ay0) + ((c & 1) ? ax1 : ax0);
        float wg = ((c & 4) ? ((c & 2) ? wzy11 : wzy10)
                            : ((c & 2) ? wzy01 : wzy00)) * ((c & 1) ? wx1 : wx0);
        uint4 q0 = ldsx[idx];
        uint4 q1 = ldsx[idx + PLANE];
        f16x2 w2 = pkrtz(wg, wg);
        a0 = __builtin_bit_cast(f16x2, q0.x) * w2 + a0;
        a1 = __builtin_bit_cast(f16x2, q0.y) * w2 + a1;
        a2 = __builtin_bit_cast(f16x2, q0.z) * w2 + a2;
        a3 = __builtin_bit_cast(f16x2, q0.w) * w2 + a3;
        a4 = __builtin_bit_cast(f16x2, q1.x) * w2 + a4;
        a5 = __builtin_bit_cast(f16x2, q1.y) * w2 + a5;
        a6 = __builtin_bit_cast(f16x2, q1.z) * w2 + a6;
        a7 = __builtin_bit_cast(f16x2, q1.w) * w2 + a7;
      }
    }
  }

  f16* yp = y + (size_t)row * CC + g * CG;
  uint4 st0, st1;
  st0.x = __builtin_bit_cast(unsigned, a0);
  st0.y = __builtin_bit_cast(unsigned, a1);
  st0.z = __builtin_bit_cast(unsigned, a2);
  st0.w = __builtin_bit_cast(unsigned, a3);
  st1.x = __builtin_bit_cast(unsigned, a4);
  st1.y = __builtin_bit_cast(unsigned, a5);
  st1.z = __builtin_bit_cast(unsigned, a6);
  st1.w = __builtin_bit_cast(unsigned, a7);
  *(uint4*)(yp)     = st0;
  *(uint4*)(yp + 8) = st1;
}

extern "C" void kernel_launch(void* const* d_in, const int* in_sizes, int n_in,
                              void* d_out, int out_size, void* d_ws, size_t ws_size,
                              hipStream_t stream) {
  const float* f_in      = (const float*)d_in[0];
  const float* value_w   = (const float*)d_in[1];
  const float* value_b   = (const float*)d_in[2];
  const float* offmask_w = (const float*)d_in[3];
  const float* offmask_b = (const float*)d_in[4];
  const float* out_w     = (const float*)d_in[5];
  const float* out_b     = (const float*)d_in[6];
  float* out = (float*)d_out;

  // ws (f16): wcat | wout | xg[16*32768*16] | om_q[216*65536*4] | y[M*128] | pbias f32
  f16* wcat = (f16*)d_ws;
  f16* wout = wcat + (size_t)PXW * CC;
  f16* xg   = wout + (size_t)CC * CC;
  f16* om   = xg + (size_t)GG * NB * LL * CG;
  f16* y    = om + (size_t)216 * MM * 4;
  float* pbias = (float*)(y + (size_t)MM * CC);

  build_pre<<<(T_ALL + 255) / 256, 256, 0, stream>>>(
      value_w, offmask_w, value_b, offmask_b, out_w, wcat, pbias, wout);

  // proj GEMM -> xg + om_q (ct-split x2)
  gemm_proj<<<dim3(MM / 64, 2), dim3(256), 0, stream>>>(
      f_in, wcat, pbias, xg, om);
  // sampling core: 8z x 8y x 2x x n2 x g8 = 2048 blocks, 256 thr
  dcn_core<<<2048, dim3(256), 0, stream>>>(xg, om, y);
  // out GEMM -> d_out f32
  gemm_out<<<dim3(MM / 64, 2), dim3(256), 0, stream>>>(y, wout, out_b, out);
}

// Round 20
// 148.133 us; speedup vs baseline: 1.0235x; 1.0235x over previous
//
#include <hip/hip_runtime.h>

// DCNv4 3D — round 20: exact revert to round-18 config (148.3 µs, best
// known). r19's proj ct-split was neutral-to-worse -> removed. All three
// kernels at mechanism-verified floors: core = LDS-b128 byte floor + 
// irreducible data-dependent jitter conflicts; proj = 6 mechanisms tested,
// only LDS B-staging moved it; out = HBM-write bound.

typedef _Float16 f16;
typedef _Float16 f16x8 __attribute__((ext_vector_type(8)));
typedef _Float16 f16x4 __attribute__((ext_vector_type(4)));
typedef _Float16 f16x2 __attribute__((ext_vector_type(2)));
typedef float    f32x4 __attribute__((ext_vector_type(4)));

#define NB 2
#define DIM 32
#define CC 128
#define GG 8
#define CG 16
#define KPTS 27
#define LL (DIM*DIM*DIM)  // 32768
#define MM (NB*LL)        // 65536
#define OMD 864
#define PXW (CC + OMD)    // 992

// halo geometry (uint4 units): v = lz*192 + ly*24 + lx ; chd plane 1536
#define SZV 192
#define SYV 24
#define PLANE 1536

// B-panel LDS row stride (f16)
#define BST 152

__device__ __forceinline__ f16x2 pkrtz(float a, float b) {
  return __builtin_bit_cast(f16x2, __builtin_amdgcn_cvt_pkrtz(a, b));
}

// ---- merged prologue ----
#define T_WCAT (PXW * 32)
#define T_WOUT (CC * CC / 4)
#define T_ALL  (T_WCAT + T_WOUT + PXW)
__global__ __launch_bounds__(256) void build_pre(
    const float* __restrict__ vw, const float* __restrict__ ow,
    const float* __restrict__ vb, const float* __restrict__ ob,
    const float* __restrict__ outw, f16* __restrict__ wcat,
    float* __restrict__ pbias, f16* __restrict__ wout) {
  int t = blockIdx.x * 256 + threadIdx.x;
  if (t < T_WCAT) {
    int p = t >> 5, c4 = (t & 31) * 4;
    const float* src;
    if (p < CC) {
      src = vw + (size_t)p * CC;
    } else {
      int q = p - CC, g = q / 108, r = q % 108, k = r >> 2, j = r & 3;
      src = ow + (size_t)(g * 108 + (j < 3 ? k * 3 + j : 81 + k)) * CC;
    }
    float4 v = *(const float4*)(src + c4);
    f16x4 o = {(f16)v.x, (f16)v.y, (f16)v.z, (f16)v.w};
    *(f16x4*)(wcat + (size_t)p * CC + c4) = o;
    return;
  }
  int u = t - T_WCAT;
  if (u < T_WOUT) {
    float4 v = ((const float4*)outw)[u];
    f16x4 o = {(f16)v.x, (f16)v.y, (f16)v.z, (f16)v.w};
    ((f16x4*)wout)[u] = o;
    return;
  }
  int p = u - T_WOUT;
  if (p < PXW) {
    float v;
    if (p < CC) v = vb[p];
    else {
      int q = p - CC, g = q / 108, r = q % 108, k = r >> 2, j = r & 3;
      v = ob[g * 108 + (j < 3 ? k * 3 + j : 81 + k)];
    }
    pbias[p] = v;
  }
}

// ---------------- proj GEMM (round-18/17/14 verbatim) ---------------------
__global__ __launch_bounds__(256) void gemm_proj(
    const float* __restrict__ A, const f16* __restrict__ B,
    const float* __restrict__ bias, f16* __restrict__ xg,
    f16* __restrict__ om) {
  __shared__ f16 bs[2][32 * BST];      // 19456 B
  __shared__ f16 tr[4][16 * 40];       // 5120 B
  const int tid  = threadIdx.x;
  const int w    = tid >> 6;
  const int lane = tid & 63;
  const int rowBase = blockIdx.x * 64 + w * 16;
  const int r  = lane & 15;
  const int kg = lane >> 4;

  f16x8 a[4];
  {
    const float* Ap = A + (size_t)(rowBase + r) * CC + kg * 8;
#pragma unroll
    for (int kk = 0; kk < 4; ++kk) {
      float4 lo = *(const float4*)(Ap + kk * 32);
      float4 hi = *(const float4*)(Ap + kk * 32 + 4);
      f16x8 t;
      t[0] = (f16)lo.x; t[1] = (f16)lo.y; t[2] = (f16)lo.z; t[3] = (f16)lo.w;
      t[4] = (f16)hi.x; t[5] = (f16)hi.y; t[6] = (f16)hi.z; t[7] = (f16)hi.w;
      a[kk] = t;
    }
  }

  uint4 stg0, stg1;
  const int i0 = tid, i1 = tid + 256;
  const int d0 = (i0 >> 4) * BST + (i0 & 15) * 8;
  const int d1 = (i1 >> 4) * BST + (i1 & 15) * 8;

  {
    const f16* src = B;
    stg0 = *(const uint4*)(src + i0 * 8);
    stg1 = *(const uint4*)(src + i1 * 8);
    *(uint4*)(bs[0] + d0) = stg0;
    *(uint4*)(bs[0] + d1) = stg1;
  }
  __syncthreads();

  f16* tw = tr[w];
  for (int ct = 0; ct < 31; ++ct) {
    const int buf = ct & 1;
    if (ct + 1 < 31) {
      const f16* src = B + (ct + 1) * 4096;
      stg0 = *(const uint4*)(src + i0 * 8);
      stg1 = *(const uint4*)(src + i1 * 8);
    }
    const f16* bp = bs[buf];
    f32x4 acc0 = {0.f, 0.f, 0.f, 0.f};
    f32x4 acc1 = {0.f, 0.f, 0.f, 0.f};
#pragma unroll
    for (int kk = 0; kk < 4; ++kk) {
      f16x8 b0 = *(const f16x8*)(bp + r * BST + kg * 8 + kk * 32);
      f16x8 b1 = *(const f16x8*)(bp + (r + 16) * BST + kg * 8 + kk * 32);
      acc0 = __builtin_amdgcn_mfma_f32_16x16x32_f16(a[kk], b0, acc0, 0, 0, 0);
      acc1 = __builtin_amdgcn_mfma_f32_16x16x32_f16(a[kk], b1, acc1, 0, 0, 0);
    }
    const int colBase = ct * 32;
    const float bv0 = bias[colBase + r];
    const float bv1 = bias[colBase + 16 + r];
#pragma unroll
    for (int i = 0; i < 4; ++i) {
      const int trow = kg * 4 + i;
      tw[trow * 40 + r]      = (f16)(acc0[i] + bv0);
      tw[trow * 40 + 16 + r] = (f16)(acc1[i] + bv1);
    }
    asm volatile("s_waitcnt lgkmcnt(0)" ::: "memory");
    const int lrow = lane >> 2;
    const int c8   = (lane & 3) * 8;
    uint4 val = *(const uint4*)(tw + lrow * 40 + c8);
    const int row  = rowBase + lrow;
    if (ct < 4) {
      const int nn = row >> 15, flat = row & (LL - 1);
      const int g  = ct * 2 + ((lane >> 1) & 1);
      unsigned e = ((unsigned)((g * 2 + nn) << 15) + flat) * 16 + (lane & 1) * 8;
      *(uint4*)(xg + e) = val;
    } else {
      const int q0 = ct * 8 - 32 + (lane & 3) * 2;
      uint2 s0, s1;
      s0.x = val.x; s0.y = val.y;
      s1.x = val.z; s1.y = val.w;
      *(uint2*)(om + ((size_t)q0 * MM + row) * 4)       = s0;
      *(uint2*)(om + ((size_t)(q0 + 1) * MM + row) * 4) = s1;
    }
    asm volatile("s_waitcnt lgkmcnt(0)" ::: "memory");
    if (ct + 1 < 31) {
      *(uint4*)(bs[buf ^ 1] + d0) = stg0;
      *(uint4*)(bs[buf ^ 1] + d1) = stg1;
    }
    __syncthreads();
  }
}

// ---------------- out GEMM ----------------------------------------------
__global__ __launch_bounds__(256) void gemm_out(
    const f16* __restrict__ Ain, const f16* __restrict__ B,
    const float* __restrict__ bias, float* __restrict__ fout) {
  const int w    = threadIdx.x >> 6;
  const int lane = threadIdx.x & 63;
  const int rowBase = blockIdx.x * 64 + w * 16;
  const int r  = lane & 15;
  const int kg = lane >> 4;
  const int ctBegin = blockIdx.y * 2;

  f16x8 a[4];
  const f16* A = Ain + (size_t)(rowBase + r) * CC + kg * 8;
#pragma unroll
  for (int kk = 0; kk < 4; ++kk) a[kk] = *(const f16x8*)(A + kk * 32);

  f16x8 bb[2][8];
#pragma unroll
  for (int s = 0; s < 2; ++s) {
    const f16* Bp = B + (unsigned)((ctBegin + s) * 32 + r) * CC + kg * 8;
#pragma unroll
    for (int kk = 0; kk < 4; ++kk) {
      bb[s][kk]     = *(const f16x8*)(Bp + kk * 32);
      bb[s][4 + kk] = *(const f16x8*)(Bp + 16 * CC + kk * 32);
    }
  }

#pragma unroll
  for (int t = 0; t < 2; ++t) {
    const int colBase = (ctBegin + t) * 32;
    f32x4 acc0 = {0.f, 0.f, 0.f, 0.f};
    f32x4 acc1 = {0.f, 0.f, 0.f, 0.f};
#pragma unroll
    for (int kk = 0; kk < 4; ++kk) {
      acc0 = __builtin_amdgcn_mfma_f32_16x16x32_f16(a[kk], bb[t][kk], acc0, 0, 0, 0);
      acc1 = __builtin_amdgcn_mfma_f32_16x16x32_f16(a[kk], bb[t][4 + kk], acc1, 0, 0, 0);
    }
    const float bv0 = bias[colBase + r];
    const float bv1 = bias[colBase + 16 + r];
    const int drow = rowBase + kg * 4;
    const int c0 = colBase + r, c1 = c0 + 16;
#pragma unroll
    for (int i = 0; i < 4; ++i) {
      unsigned ro = (unsigned)(drow + i) * CC;
      fout[ro + c0] = acc0[i] + bv0;
      fout[ro + c1] = acc1[i] + bv1;
    }
  }
}

// ---------------- DCNv4 sampling core v11 (round-18 verbatim) ------------
__global__ __launch_bounds__(256) void dcn_core(const f16* __restrict__ xg,
                                                const f16* __restrict__ om,
                                                f16* __restrict__ y) {
  __shared__ uint4 ldsx[2 * PLANE];   // 49152 B

  const int tid = threadIdx.x;
  int bid = blockIdx.x;
  const int g   = bid & 7;        bid >>= 3;
  const int n   = bid & 1;        bid >>= 1;
  const int tx0 = (bid & 1) * 16; bid >>= 1;
  const int ty0 = (bid & 7) * 4;  bid >>= 3;
  const int tz0 = bid * 4;

  // ---- stage halo 8z x 8y x 20x, zero-padded ----
  const f16* xgb = xg + (((size_t)(g * 2 + n)) << 15) * 16;
#pragma unroll
  for (int it = 0; it < 5; ++it) {
    int v = tid + it * 256;            // 0..1279
    int lz = v / 160, r160 = v - lz * 160;
    int ly = r160 / 20, lx = r160 - ly * 20;
    int gz = tz0 - 2 + lz, gy = ty0 - 2 + ly, gx = tx0 - 2 + lx;
    uint4 d0 = {0u, 0u, 0u, 0u}, d1 = {0u, 0u, 0u, 0u};
    if (((unsigned)gz < DIM) & ((unsigned)gy < DIM) & ((unsigned)gx < DIM)) {
      const uint4* src = (const uint4*)(xgb + (size_t)(((gz << 5) + gy) * 32 + gx) * 16);
      d0 = src[0];
      d1 = src[1];
    }
    int vv = lz * SZV + ly * SYV + lx;
    ldsx[vv]         = d0;
    ldsx[PLANE + vv] = d1;
  }
  __syncthreads();

  // ---- sampling: lane = position ----
  const int px = tid & 15, py = (tid >> 4) & 3, pz = tid >> 6;
  const int dz = tz0 + pz, dy = ty0 + py, dx = tx0 + px;
  const unsigned row = (unsigned)(n << 15) + ((dz << 10) + (dy << 5) + dx);

  const int zoff = tz0 - 2, yoff = ty0 - 2, xoff = tx0 - 2;
  const int pb = g * 27;                    // om plane base

  float dyf[3], dxf[3];
#pragma unroll
  for (int t = 0; t < 3; ++t) { dyf[t] = (float)(dy + t - 1); dxf[t] = (float)(dx + t - 1); }

  f16x2 a0 = {(f16)0, (f16)0}, a1 = a0, a2 = a0, a3 = a0;
  f16x2 a4 = a0, a5 = a0, a6 = a0, a7 = a0;
  const float CL = 0.99902344f;

  for (int kz = 0; kz < 3; ++kz) {
    const float bzf = (float)(dz + kz - 1);
    uint2 o[9];
#pragma unroll
    for (int j = 0; j < 9; ++j)
      o[j] = *(const uint2*)(om + ((size_t)(pb + kz * 9 + j) * MM + row) * 4);
#pragma unroll
    for (int j = 0; j < 9; ++j) {
      const int kh = j / 3, kw = j % 3;
      f16x2 o01 = __builtin_bit_cast(f16x2, o[j].x);
      f16x2 o23 = __builtin_bit_cast(f16x2, o[j].y);
      float od = fminf(fmaxf((float)o01[0], -CL), CL);
      float oh = fminf(fmaxf((float)o01[1], -CL), CL);
      float ow = fminf(fmaxf((float)o23[0], -CL), CL);
      float m  = (float)o23[1];
      float pd = bzf + od;
      float ph = dyf[kh] + oh;
      float pw = dxf[kw] + ow;
      float fd = floorf(pd), fh = floorf(ph), fw = floorf(pw);
      float td = pd - fd, th = ph - fh, tw = pw - fw;
      int id = (int)fd, ih = (int)fh, iw = (int)fw;
      float wz0 = (1.f - td) * m, wz1 = td * m;
      float wy0 = 1.f - th,        wy1 = th;
      float wx0 = 1.f - tw,        wx1 = tw;
      int az0 = (id - zoff) * SZV, az1 = az0 + SZV;
      int ay0 = (ih - yoff) * SYV, ay1 = ay0 + SYV;
      int ax0 = (iw - xoff), ax1 = ax0 + 1;
      float wzy00 = wz0 * wy0, wzy01 = wz0 * wy1;
      float wzy10 = wz1 * wy0, wzy11 = wz1 * wy1;
#pragma unroll
      for (int c = 0; c < 8; ++c) {
        int idx = ((c & 4) ? az1 : az0) + ((c & 2) ? ay1 : ay0) + ((c & 1) ? ax1 : ax0);
        float wg = ((c & 4) ? ((c & 2) ? wzy11 : wzy10)
                            : ((c & 2) ? wzy01 : wzy00)) * ((c & 1) ? wx1 : wx0);
        uint4 q0 = ldsx[idx];
        uint4 q1 = ldsx[idx + PLANE];
        f16x2 w2 = pkrtz(wg, wg);
        a0 = __builtin_bit_cast(f16x2, q0.x) * w2 + a0;
        a1 = __builtin_bit_cast(f16x2, q0.y) * w2 + a1;
        a2 = __builtin_bit_cast(f16x2, q0.z) * w2 + a2;
        a3 = __builtin_bit_cast(f16x2, q0.w) * w2 + a3;
        a4 = __builtin_bit_cast(f16x2, q1.x) * w2 + a4;
        a5 = __builtin_bit_cast(f16x2, q1.y) * w2 + a5;
        a6 = __builtin_bit_cast(f16x2, q1.z) * w2 + a6;
        a7 = __builtin_bit_cast(f16x2, q1.w) * w2 + a7;
      }
    }
  }

  f16* yp = y + (size_t)row * CC + g * CG;
  uint4 st0, st1;
  st0.x = __builtin_bit_cast(unsigned, a0);
  st0.y = __builtin_bit_cast(unsigned, a1);
  st0.z = __builtin_bit_cast(unsigned, a2);
  st0.w = __builtin_bit_cast(unsigned, a3);
  st1.x = __builtin_bit_cast(unsigned, a4);
  st1.y = __builtin_bit_cast(unsigned, a5);
  st1.z = __builtin_bit_cast(unsigned, a6);
  st1.w = __builtin_bit_cast(unsigned, a7);
  *(uint4*)(yp)     = st0;
  *(uint4*)(yp + 8) = st1;
}

extern "C" void kernel_launch(void* const* d_in, const int* in_sizes, int n_in,
                              void* d_out, int out_size, void* d_ws, size_t ws_size,
                              hipStream_t stream) {
  const float* f_in      = (const float*)d_in[0];
  const float* value_w   = (const float*)d_in[1];
  const float* value_b   = (const float*)d_in[2];
  const float* offmask_w = (const float*)d_in[3];
  const float* offmask_b = (const float*)d_in[4];
  const float* out_w     = (const float*)d_in[5];
  const float* out_b     = (const float*)d_in[6];
  float* out = (float*)d_out;

  // ws (f16): wcat | wout | xg[16*32768*16] | om_q[216*65536*4] | y[M*128] | pbias f32
  f16* wcat = (f16*)d_ws;
  f16* wout = wcat + (size_t)PXW * CC;
  f16* xg   = wout + (size_t)CC * CC;
  f16* om   = xg + (size_t)GG * NB * LL * CG;
  f16* y    = om + (size_t)216 * MM * 4;
  float* pbias = (float*)(y + (size_t)MM * CC);

  build_pre<<<(T_ALL + 255) / 256, 256, 0, stream>>>(
      value_w, offmask_w, value_b, offmask_b, out_w, wcat, pbias, wout);

  // proj GEMM -> xg + om_q
  gemm_proj<<<MM / 64, dim3(256), 0, stream>>>(f_in, wcat, pbias, xg, om);
  // sampling core: 8z x 8y x 2x x n2 x g8 = 2048 blocks, 256 thr
  dcn_core<<<2048, dim3(256), 0, stream>>>(xg, om, y);
  // out GEMM -> d_out f32
  gemm_out<<<dim3(MM / 64, 2), dim3(256), 0, stream>>>(y, wout, out_b, out);
}